// Round 1
// baseline (1596.225 us; speedup 1.0000x reference)
//
#include <hip/hip_runtime.h>
#include <cstdint>
#include <cstddef>

#define N_TOT 10000
#define CDIM  128
#define TK    50
#define NHID_ 256
#define NCLS  10
#define GAMMA_REG 0.01f
#define BN_EPS 1e-5f

__device__ __forceinline__ float waveSumF(float v){
  #pragma unroll
  for (int o=32;o;o>>=1) v += __shfl_xor(v,o,64);
  return v;
}
__device__ __forceinline__ float waveMaxF(float v){
  #pragma unroll
  for (int o=32;o;o>>=1) v = fmaxf(v,__shfl_xor(v,o,64));
  return v;
}
__device__ __forceinline__ int waveSumI(int v){
  #pragma unroll
  for (int o=32;o;o>>=1) v += __shfl_xor(v,o,64);
  return v;
}

// ---------------- generic 64x64 fp32 GEMM: C = A[MxK] @ B[KxN] (+bias) ----------
// assumes K % 32 == 0, N % 64 == 0; guards M edge.
template<bool BIAS>
__global__ __launch_bounds__(256) void gemm64(const float* __restrict__ A,
                                              const float* __restrict__ B,
                                              const float* __restrict__ bias,
                                              float* __restrict__ C,
                                              int M, int N, int K){
  constexpr int BK=32;
  __shared__ float As[BK][64+4];
  __shared__ float Bs[BK][64+4];
  const int tid = threadIdx.x;
  const int bm = blockIdx.y*64, bn = blockIdx.x*64;
  const int tm = (tid>>4)<<2;
  const int tn = (tid&15)<<2;
  float acc[4][4] = {};
  for (int k0=0;k0<K;k0+=BK){
    #pragma unroll
    for (int i=0;i<2;++i){             // A tile 64x32 = 512 float4
      int fi = tid + i*256;
      int r  = fi>>3;                  // 8 float4 per row
      int c4 = fi&7;
      float4 v = make_float4(0,0,0,0);
      int gr = bm + r;
      if (gr < M) v = *(const float4*)(A + (size_t)gr*K + k0 + (c4<<2));
      As[(c4<<2)+0][r]=v.x; As[(c4<<2)+1][r]=v.y; As[(c4<<2)+2][r]=v.z; As[(c4<<2)+3][r]=v.w;
    }
    #pragma unroll
    for (int i=0;i<2;++i){             // B tile 32x64 = 512 float4
      int fi = tid + i*256;
      int r  = fi>>4;                  // 16 float4 per row
      int c4 = fi&15;
      float4 v = *(const float4*)(B + (size_t)(k0+r)*N + bn + (c4<<2));
      *(float4*)&Bs[r][c4<<2] = v;
    }
    __syncthreads();
    #pragma unroll
    for (int kk=0;kk<BK;++kk){
      float a[4], b[4];
      *(float4*)a = *(const float4*)&As[kk][tm];
      *(float4*)b = *(const float4*)&Bs[kk][tn];
      #pragma unroll
      for (int i=0;i<4;++i)
        #pragma unroll
        for (int j=0;j<4;++j) acc[i][j] = fmaf(a[i], b[j], acc[i][j]);
    }
    __syncthreads();
  }
  #pragma unroll
  for (int i=0;i<4;++i){
    int gr = bm+tm+i;
    if (gr < M){
      float4 o; o.x=acc[i][0]; o.y=acc[i][1]; o.z=acc[i][2]; o.w=acc[i][3];
      if (BIAS){
        o.x += bias[bn+tn+0]; o.y += bias[bn+tn+1];
        o.z += bias[bn+tn+2]; o.w += bias[bn+tn+3];
      }
      *(float4*)(C + (size_t)gr*N + bn + tn) = o;
    }
  }
}

// ---------------- per-chunk BatchNorm (training stats, biased var), in place ----
__global__ void bn_kernel(float* __restrict__ feat, const float* __restrict__ g,
                          const float* __restrict__ b){
  int chunk = blockIdx.x;        // 100 chunks of 100 rows
  int c = threadIdx.x;           // 128 channels
  float* base = feat + (size_t)chunk*100*CDIM;
  float s=0.f, s2=0.f;
  for (int r=0;r<100;++r){ float v = base[r*CDIM+c]; s += v; s2 += v*v; }
  float mu  = s * 0.01f;
  float var = s2 * 0.01f - mu*mu;
  float sc  = g[c] * rsqrtf(var + BN_EPS);
  float sh  = b[c] - mu*sc;
  for (int r=0;r<100;++r){ base[r*CDIM+c] = base[r*CDIM+c]*sc + sh; }
}

// ---------------- p[i] = sum_c a_c f_ic^2 ; xn[i] = sum_c f_ic^2 ---------------
__global__ __launch_bounds__(256) void pxn_kernel(const float* __restrict__ feat,
                                                  const float* __restrict__ aS,
                                                  float* __restrict__ p,
                                                  float* __restrict__ xn){
  int wave = threadIdx.x>>6, lane = threadIdx.x&63;
  int row = blockIdx.x*4 + wave;
  const float2 f = ((const float2*)(feat + (size_t)row*CDIM))[lane];
  const float2 a = ((const float2*)aS)[lane];
  float sp = a.x*f.x*f.x + a.y*f.y*f.y;
  float sx = f.x*f.x + f.y*f.y;
  sp = waveSumF(sp); sx = waveSumF(sx);
  if (lane==0){ p[row]=sp; xn[row]=sx; }
}

// -------- scores[i][j] = relu(p_i + p_j + b - 2 * sum_c (a_c f_ic) f_jc) -------
__global__ __launch_bounds__(256) void score_gemm(const float* __restrict__ feat,
                                                  const float* __restrict__ aS,
                                                  const float* __restrict__ p,
                                                  const float* __restrict__ bS,
                                                  float* __restrict__ scores){
  constexpr int BK=32;
  __shared__ float As[BK][128+4];
  __shared__ float Bs[BK][128+4];
  const int tid = threadIdx.x;
  const int bm = blockIdx.y*128, bn = blockIdx.x*128;
  const int tm = (tid>>4)<<3;
  const int tn = (tid&15)<<3;
  float acc[8][8] = {};
  for (int k0=0;k0<CDIM;k0+=BK){
    #pragma unroll
    for (int i=0;i<4;++i){             // A' tile: feat rows bm.., scaled by a
      int fi = tid + i*256;            // 1024 float4 = 128 rows x 8
      int r  = fi>>3;
      int c4 = fi&7;
      float4 v = make_float4(0,0,0,0);
      int gr = bm + r;
      if (gr < N_TOT) v = *(const float4*)(feat + (size_t)gr*CDIM + k0 + (c4<<2));
      float4 av = *(const float4*)(aS + k0 + (c4<<2));
      As[(c4<<2)+0][r]=v.x*av.x; As[(c4<<2)+1][r]=v.y*av.y;
      As[(c4<<2)+2][r]=v.z*av.z; As[(c4<<2)+3][r]=v.w*av.w;
    }
    #pragma unroll
    for (int i=0;i<4;++i){             // B tile: feat rows bn..
      int fi = tid + i*256;
      int r  = fi>>3;
      int c4 = fi&7;
      float4 v = make_float4(0,0,0,0);
      int gr = bn + r;
      if (gr < N_TOT) v = *(const float4*)(feat + (size_t)gr*CDIM + k0 + (c4<<2));
      Bs[(c4<<2)+0][r]=v.x; Bs[(c4<<2)+1][r]=v.y; Bs[(c4<<2)+2][r]=v.z; Bs[(c4<<2)+3][r]=v.w;
    }
    __syncthreads();
    #pragma unroll
    for (int kk=0;kk<BK;++kk){
      float a[8], b[8];
      *(float4*)&a[0] = *(const float4*)&As[kk][tm];
      *(float4*)&a[4] = *(const float4*)&As[kk][tm+4];
      *(float4*)&b[0] = *(const float4*)&Bs[kk][tn];
      *(float4*)&b[4] = *(const float4*)&Bs[kk][tn+4];
      #pragma unroll
      for (int i=0;i<8;++i)
        #pragma unroll
        for (int j=0;j<8;++j) acc[i][j] = fmaf(a[i], b[j], acc[i][j]);
    }
    __syncthreads();
  }
  const float bb = bS[0];
  float pj[8];
  #pragma unroll
  for (int j=0;j<8;++j){ int gj = bn+tn+j; pj[j] = (gj < N_TOT) ? p[gj] : 0.f; }
  #pragma unroll
  for (int i=0;i<8;++i){
    int gi = bm+tm+i;
    if (gi >= N_TOT) break;
    float pi = p[gi];
    #pragma unroll
    for (int j4=0;j4<8;j4+=4){
      int gj = bn+tn+j4;
      if (gj+3 < N_TOT){
        float4 o;
        o.x = fmaxf(pi + pj[j4+0] + bb - 2.f*acc[i][j4+0], 0.f);
        o.y = fmaxf(pi + pj[j4+1] + bb - 2.f*acc[i][j4+1], 0.f);
        o.z = fmaxf(pi + pj[j4+2] + bb - 2.f*acc[i][j4+2], 0.f);
        o.w = fmaxf(pi + pj[j4+3] + bb - 2.f*acc[i][j4+3], 0.f);
        *(float4*)(scores + (size_t)gi*N_TOT + gj) = o;
      }
    }
  }
}

// ---------------- exact per-row top-50 + softmax -------------------------------
__global__ __launch_bounds__(256) void topk_kernel(const float* __restrict__ scores,
                                                   int* __restrict__ idxO,
                                                   float* __restrict__ softO){
  const int row = blockIdx.x, tid = threadIdx.x;
  const float4* srow = (const float4*)(scores + (size_t)row*N_TOT);
  float4 v[10];
  #pragma unroll
  for (int s=0;s<10;++s){
    int fi = tid + s*256;
    v[s] = (fi < 2500) ? srow[fi] : make_float4(-1.f,-1.f,-1.f,-1.f);
  }
  float mx = -1.f;
  #pragma unroll
  for (int s=0;s<10;++s)
    mx = fmaxf(mx, fmaxf(fmaxf(v[s].x,v[s].y), fmaxf(v[s].z,v[s].w)));
  __shared__ float redf[4];
  __shared__ int cntS;
  float wm = waveMaxF(mx);
  if ((tid&63)==0) redf[tid>>6] = wm;
  __syncthreads();
  mx = fmaxf(fmaxf(redf[0],redf[1]), fmaxf(redf[2],redf[3]));

  // integer binary search for exact 50th-largest value (positive-float bits)
  unsigned lo = 0, hi = __float_as_uint(mx);
  while (lo < hi){
    unsigned mid = (lo + hi) >> 1;
    float t = __uint_as_float(mid);
    int c = 0;
    #pragma unroll
    for (int s=0;s<10;++s)
      c += (v[s].x>t) + (v[s].y>t) + (v[s].z>t) + (v[s].w>t);
    if (tid==0) cntS = 0;
    __syncthreads();
    c = waveSumI(c);
    if ((tid&63)==0) atomicAdd(&cntS, c);
    __syncthreads();
    int total = cntS;
    __syncthreads();
    if (total >= TK) lo = mid + 1; else hi = mid;
  }
  const float v50 = __uint_as_float(lo);

  __shared__ int   selIdx[TK];
  __shared__ float selVal[TK];
  __shared__ int cSel, cTie;
  if (tid==0){ cSel=0; cTie=0; }
  __syncthreads();
  #pragma unroll
  for (int s=0;s<10;++s){
    int base = 4*(tid + s*256);
    float vals[4] = {v[s].x, v[s].y, v[s].z, v[s].w};
    #pragma unroll
    for (int e=0;e<4;++e){
      if (vals[e] > v50){ int q = atomicAdd(&cSel,1); selIdx[q]=base+e; selVal[q]=vals[e]; }
    }
  }
  __syncthreads();
  const int m = cSel;
  #pragma unroll
  for (int s=0;s<10;++s){
    int base = 4*(tid + s*256);
    float vals[4] = {v[s].x, v[s].y, v[s].z, v[s].w};
    #pragma unroll
    for (int e=0;e<4;++e){
      if (vals[e] == v50){
        int q = atomicAdd(&cTie,1);
        if (m + q < TK){ selIdx[m+q]=base+e; selVal[m+q]=v50; }
      }
    }
  }
  __syncthreads();
  if (tid < 64){
    float e = (tid < TK) ? __expf(selVal[tid] - mx) : 0.f;
    float s = waveSumF(e);
    if (tid < TK){
      softO[row*TK + tid] = e / s;
      idxO [row*TK + tid] = selIdx[tid];
    }
  }
}

// ---------------- zero loss + S (100,000,001 floats, base 16B-aligned) ---------
__global__ void zero_kernel(float* __restrict__ base){
  size_t t = (size_t)blockIdx.x*blockDim.x + threadIdx.x;
  float4* b4 = (float4*)base;
  const size_t n4 = 25000000;
  for (size_t i=t; i<n4; i += (size_t)gridDim.x*blockDim.x) b4[i] = make_float4(0,0,0,0);
  if (t==0) base[100000000] = 0.f;
}

// ---------------- scatter soft into dense S ------------------------------------
__global__ void scatter_kernel(const int* __restrict__ idx, const float* __restrict__ soft,
                               float* __restrict__ S){
  int t = blockIdx.x*blockDim.x + threadIdx.x;
  if (t < N_TOT*TK){
    int i = t / TK;
    S[(size_t)i*N_TOT + idx[t]] = soft[t];
  }
}

// ---------------- loss = sum(dp*soft) + gamma*sum(soft) ------------------------
__global__ __launch_bounds__(256) void loss_kernel(const float* __restrict__ feat,
                                                   const float* __restrict__ xn,
                                                   const int* __restrict__ idx,
                                                   const float* __restrict__ soft,
                                                   float* __restrict__ lossOut){
  int row = blockIdx.x;
  int grp = threadIdx.x>>6, lane = threadIdx.x&63;
  const float2 a = ((const float2*)(feat + (size_t)row*CDIM))[lane];
  float acc = 0.f;
  for (int k=grp; k<TK; k+=4){
    int   j = idx [row*TK + k];
    float s = soft[row*TK + k];
    const float2 b = ((const float2*)(feat + (size_t)j*CDIM))[lane];
    float d = a.x*b.x + a.y*b.y;
    d = waveSumF(d);
    if (lane==0){
      float dp = fmaxf(xn[row] + xn[j] - 2.f*d, 0.f);
      acc += s*dp + GAMMA_REG*s;
    }
  }
  __shared__ float part[4];
  if (lane==0) part[grp] = acc;
  __syncthreads();
  if (threadIdx.x==0) atomicAdd(lossOut, part[0]+part[1]+part[2]+part[3]);
}

// ---------------- h[i][c] = relu(b1[c] + sum_k soft * X1[idx_k][c]) ------------
__global__ __launch_bounds__(256) void h_kernel(const float* __restrict__ X1,
                                                const int* __restrict__ idx,
                                                const float* __restrict__ soft,
                                                const float* __restrict__ b1,
                                                float* __restrict__ h){
  int row = blockIdx.x, c = threadIdx.x;
  __shared__ int   ji[TK];
  __shared__ float sv[TK];
  if (c < TK){ ji[c]=idx[row*TK+c]; sv[c]=soft[row*TK+c]; }
  __syncthreads();
  float acc = b1[c];
  #pragma unroll 10
  for (int k=0;k<TK;++k) acc = fmaf(sv[k], X1[(size_t)ji[k]*NHID_ + c], acc);
  h[(size_t)row*NHID_ + c] = fmaxf(acc, 0.f);
}

// ---------------- X2 = h @ W2 (W2 in LDS) --------------------------------------
__global__ __launch_bounds__(256) void x2_kernel(const float* __restrict__ h,
                                                 const float* __restrict__ W2,
                                                 float* __restrict__ X2){
  __shared__ float w[NHID_*NCLS];
  for (int i=threadIdx.x; i<NHID_*NCLS; i+=256) w[i] = W2[i];
  __syncthreads();
  int t = blockIdx.x*256 + threadIdx.x;
  if (t < N_TOT*NCLS){
    int r = t / NCLS, c = t % NCLS;
    float acc = 0.f;
    const float* hr = h + (size_t)r*NHID_;
    #pragma unroll 8
    for (int k=0;k<NHID_;++k) acc = fmaf(hr[k], w[k*NCLS+c], acc);
    X2[t] = acc;
  }
}

// ------- logits[i][c] = b2[c] + sum_k soft*X2[idx_k][c]; semi = log_softmax ----
__global__ __launch_bounds__(64) void logits_kernel(const float* __restrict__ X2,
                                                    const int* __restrict__ idx,
                                                    const float* __restrict__ soft,
                                                    const float* __restrict__ b2,
                                                    float* __restrict__ semi){
  int row = blockIdx.x, tid = threadIdx.x;
  __shared__ int   ji[TK];
  __shared__ float sv[TK];
  if (tid < TK){ ji[tid]=idx[row*TK+tid]; sv[tid]=soft[row*TK+tid]; }
  __syncthreads();
  float acc = 0.f;
  if (tid < NCLS){
    acc = b2[tid];
    for (int k=0;k<TK;++k) acc = fmaf(sv[k], X2[(size_t)ji[k]*NCLS + tid], acc);
  }
  float mv = (tid < NCLS) ? acc : -1e30f;
  #pragma unroll
  for (int o=8;o;o>>=1) mv = fmaxf(mv, __shfl_xor(mv,o,16));
  float e = (tid < NCLS) ? __expf(acc - mv) : 0.f;
  #pragma unroll
  for (int o=8;o;o>>=1) e += __shfl_xor(e,o,16);
  if (tid < NCLS) semi[row*NCLS + tid] = acc - mv - logf(e);
}

extern "C" void kernel_launch(void* const* d_in, const int* in_sizes, int n_in,
                              void* d_out, int out_size, void* d_ws, size_t ws_size,
                              hipStream_t stream){
  const float* inputs   = (const float*)d_in[0];   // [10000,3072]
  const float* W_lin    = (const float*)d_in[1];   // [3072,128]
  const float* b_lin    = (const float*)d_in[2];
  const float* bn_gamma = (const float*)d_in[3];
  const float* bn_beta  = (const float*)d_in[4];
  const float* a_S      = (const float*)d_in[5];
  const float* b_S      = (const float*)d_in[6];
  const float* W1       = (const float*)d_in[7];   // [128,256]
  const float* b1       = (const float*)d_in[8];
  const float* W2       = (const float*)d_in[9];   // [256,10]
  const float* b2       = (const float*)d_in[10];

  float* out  = (float*)d_out;
  float* ws   = (float*)d_ws;

  // ws layout (floats); total 7.52M floats = 30.1 MB
  float* feat = ws;                       // 1,280,000
  float* p    = ws + 1280000;             // 10,000
  float* xn   = ws + 1290000;             // 10,000
  int*   idxb = (int*)(ws + 1300000);     // 500,000
  float* soft = ws + 1800000;             // 500,000
  float* X1   = ws + 2300000;             // 2,560,000
  float* hbuf = ws + 4860000;             // 2,560,000
  float* X2   = ws + 7420000;             // 100,000

  // d_out layout: semi[100000], loss[1], S[1e8]
  float* semi    = out;
  float* lossOut = out + 100000;          // 16B-aligned
  float* Sout    = out + 100001;
  float* scratch = out + 100000;          // score matrix scratch (overwritten later)

  // 1. lin = inputs @ W_lin + b_lin   -> feat (pre-BN)
  gemm64<true><<<dim3(2,157), 256, 0, stream>>>(inputs, W_lin, b_lin, feat, N_TOT, CDIM, 3072);
  // 2. per-chunk BN in place
  bn_kernel<<<100, CDIM, 0, stream>>>(feat, bn_gamma, bn_beta);
  // 3. p, xn
  pxn_kernel<<<2500, 256, 0, stream>>>(feat, a_S, p, xn);
  // 4. scores -> scratch (in S region of d_out)
  score_gemm<<<dim3(79,79), 256, 0, stream>>>(feat, a_S, p, b_S, scratch);
  // 5. X1 = feat @ W1
  gemm64<false><<<dim3(4,157), 256, 0, stream>>>(feat, W1, nullptr, X1, N_TOT, NHID_, CDIM);
  // 6. exact top-50 + softmax
  topk_kernel<<<N_TOT, 256, 0, stream>>>(scratch, idxb, soft);
  // 7. zero loss + S
  zero_kernel<<<4096, 256, 0, stream>>>(lossOut);
  // 8. scatter S
  scatter_kernel<<<(N_TOT*TK+255)/256, 256, 0, stream>>>(idxb, soft, Sout);
  // 9. loss
  loss_kernel<<<N_TOT, 256, 0, stream>>>(feat, xn, idxb, soft, lossOut);
  // 10. h = relu(S@X1 + b1)
  h_kernel<<<N_TOT, NHID_, 0, stream>>>(X1, idxb, soft, b1, hbuf);
  // 11. X2 = h @ W2
  x2_kernel<<<(N_TOT*NCLS+255)/256, 256, 0, stream>>>(hbuf, W2, X2);
  // 12. logits + log_softmax -> semi
  logits_kernel<<<N_TOT, 64, 0, stream>>>(X2, idxb, soft, b2, semi);
}

// Round 3
// 1476.388 us; speedup vs baseline: 1.0812x; 1.0812x over previous
//
#include <hip/hip_runtime.h>
#include <hip/hip_bf16.h>
#include <cstdint>
#include <cstddef>

#define N_TOT 10000
#define CDIM  128
#define TK    50
#define NHID_ 256
#define NCLS  10
#define GAMMA_REG 0.01f
#define BN_EPS 1e-5f

typedef float f32x4 __attribute__((ext_vector_type(4)));
typedef short s16x8 __attribute__((ext_vector_type(8)));

__device__ __forceinline__ float waveSumF(float v){
  #pragma unroll
  for (int o=32;o;o>>=1) v += __shfl_xor(v,o,64);
  return v;
}
__device__ __forceinline__ float waveMaxF(float v){
  #pragma unroll
  for (int o=32;o;o>>=1) v = fmaxf(v,__shfl_xor(v,o,64));
  return v;
}
__device__ __forceinline__ int waveSumI(int v){
  #pragma unroll
  for (int o=32;o;o>>=1) v += __shfl_xor(v,o,64);
  return v;
}
__device__ __forceinline__ ushort bfh(float f){
  __hip_bfloat16 h = __float2bfloat16(f);          // RNE
  return *reinterpret_cast<ushort*>(&h);
}
__device__ __forceinline__ float bf2f(ushort u){
  __hip_bfloat16 h = *reinterpret_cast<__hip_bfloat16*>(&u);
  return __bfloat162float(h);
}

// ---------------- generic 64x64 fp32 GEMM: C = A[MxK] @ B[KxN] (+bias) ----------
template<bool BIAS>
__global__ __launch_bounds__(256) void gemm64(const float* __restrict__ A,
                                              const float* __restrict__ B,
                                              const float* __restrict__ bias,
                                              float* __restrict__ C,
                                              int M, int N, int K){
  constexpr int BK=32;
  __shared__ float As[BK][64+4];
  __shared__ float Bs[BK][64+4];
  const int tid = threadIdx.x;
  const int bm = blockIdx.y*64, bn = blockIdx.x*64;
  const int tm = (tid>>4)<<2;
  const int tn = (tid&15)<<2;
  float acc[4][4] = {};
  for (int k0=0;k0<K;k0+=BK){
    #pragma unroll
    for (int i=0;i<2;++i){
      int fi = tid + i*256;
      int r  = fi>>3;
      int c4 = fi&7;
      float4 v = make_float4(0,0,0,0);
      int gr = bm + r;
      if (gr < M) v = *(const float4*)(A + (size_t)gr*K + k0 + (c4<<2));
      As[(c4<<2)+0][r]=v.x; As[(c4<<2)+1][r]=v.y; As[(c4<<2)+2][r]=v.z; As[(c4<<2)+3][r]=v.w;
    }
    #pragma unroll
    for (int i=0;i<2;++i){
      int fi = tid + i*256;
      int r  = fi>>4;
      int c4 = fi&15;
      float4 v = *(const float4*)(B + (size_t)(k0+r)*N + bn + (c4<<2));
      *(float4*)&Bs[r][c4<<2] = v;
    }
    __syncthreads();
    #pragma unroll
    for (int kk=0;kk<BK;++kk){
      float a[4], b[4];
      *(float4*)a = *(const float4*)&As[kk][tm];
      *(float4*)b = *(const float4*)&Bs[kk][tn];
      #pragma unroll
      for (int i=0;i<4;++i)
        #pragma unroll
        for (int j=0;j<4;++j) acc[i][j] = fmaf(a[i], b[j], acc[i][j]);
    }
    __syncthreads();
  }
  #pragma unroll
  for (int i=0;i<4;++i){
    int gr = bm+tm+i;
    if (gr < M){
      float4 o; o.x=acc[i][0]; o.y=acc[i][1]; o.z=acc[i][2]; o.w=acc[i][3];
      if (BIAS){
        o.x += bias[bn+tn+0]; o.y += bias[bn+tn+1];
        o.z += bias[bn+tn+2]; o.w += bias[bn+tn+3];
      }
      *(float4*)(C + (size_t)gr*N + bn + tn) = o;
    }
  }
}

// ---------------- per-chunk BatchNorm (training stats, biased var), in place ----
__global__ void bn_kernel(float* __restrict__ feat, const float* __restrict__ g,
                          const float* __restrict__ b){
  int chunk = blockIdx.x;
  int c = threadIdx.x;
  float* base = feat + (size_t)chunk*100*CDIM;
  float s=0.f, s2=0.f;
  for (int r=0;r<100;++r){ float v = base[r*CDIM+c]; s += v; s2 += v*v; }
  float mu  = s * 0.01f;
  float var = s2 * 0.01f - mu*mu;
  float sc  = g[c] * rsqrtf(var + BN_EPS);
  float sh  = b[c] - mu*sc;
  for (int r=0;r<100;++r){ base[r*CDIM+c] = base[r*CDIM+c]*sc + sh; }
}

// ------- split feat into bf16 hi/lo (plain: fh/fl, a-scaled: gh/gl) + p, xn ----
__global__ __launch_bounds__(256) void featsplit(const float* __restrict__ feat,
                                                 const float* __restrict__ aS,
                                                 ushort* __restrict__ fh, ushort* __restrict__ fl,
                                                 ushort* __restrict__ gh, ushort* __restrict__ gl,
                                                 float* __restrict__ p, float* __restrict__ xn){
  int wave = threadIdx.x>>6, lane = threadIdx.x&63;
  int row = blockIdx.x*4 + wave;
  const float2 f = ((const float2*)(feat + (size_t)row*CDIM))[lane];
  const float2 a = ((const float2*)aS)[lane];
  float gx = f.x*a.x, gy = f.y*a.y;

  ushort2 v;
  size_t o = (size_t)row*64 + lane;
  v.x = bfh(f.x); v.y = bfh(f.y);
  ((ushort2*)fh)[o] = v;
  ushort2 vl; vl.x = bfh(f.x - bf2f(v.x)); vl.y = bfh(f.y - bf2f(v.y));
  ((ushort2*)fl)[o] = vl;
  ushort2 w; w.x = bfh(gx); w.y = bfh(gy);
  ((ushort2*)gh)[o] = w;
  ushort2 wl2; wl2.x = bfh(gx - bf2f(w.x)); wl2.y = bfh(gy - bf2f(w.y));
  ((ushort2*)gl)[o] = wl2;

  float sp = gx*f.x + gy*f.y;
  float sx = f.x*f.x + f.y*f.y;
  sp = waveSumF(sp); sx = waveSumF(sx);
  if (lane==0){ p[row]=sp; xn[row]=sx; }
}

// -------- scores[i][j] = relu(p_i + p_j + b - 2 * (g_i . f_j)), split-bf16 MFMA -
__global__ __launch_bounds__(256) void score_mfma(const ushort* __restrict__ fh,
                                                  const ushort* __restrict__ fl,
                                                  const ushort* __restrict__ gh,
                                                  const ushort* __restrict__ gl,
                                                  const float* __restrict__ p,
                                                  const float* __restrict__ bS,
                                                  float* __restrict__ scores){
  const int lane = threadIdx.x & 63;
  const int wave = threadIdx.x >> 6;
  const int wm = wave >> 1, wn = wave & 1;
  const int bm = blockIdx.y*128 + wm*64;
  const int bn = blockIdx.x*128 + wn*64;
  const int lr = lane & 15;
  const int kb = lane >> 4;
  f32x4 acc[4][4] = {};

  int arow[4], brow[4];
  #pragma unroll
  for (int i=0;i<4;++i){
    int r = bm + i*16 + lr; arow[i] = (r < N_TOT ? r : N_TOT-1);
    int c = bn + i*16 + lr; brow[i] = (c < N_TOT ? c : N_TOT-1);
  }

  #pragma unroll 1
  for (int k0=0;k0<CDIM;k0+=32){
    const int ko = k0 + kb*8;
    s16x8 ah[4], al[4], bh[4], bl[4];
    #pragma unroll
    for (int i=0;i<4;++i){
      size_t ao = (size_t)arow[i]*CDIM + ko;
      size_t bo = (size_t)brow[i]*CDIM + ko;
      ah[i] = *(const s16x8*)(gh + ao);
      al[i] = *(const s16x8*)(gl + ao);
      bh[i] = *(const s16x8*)(fh + bo);
      bl[i] = *(const s16x8*)(fl + bo);
    }
    #pragma unroll
    for (int i=0;i<4;++i)
      #pragma unroll
      for (int j=0;j<4;++j){
        acc[i][j] = __builtin_amdgcn_mfma_f32_16x16x32_bf16(ah[i], bh[j], acc[i][j], 0,0,0);
        acc[i][j] = __builtin_amdgcn_mfma_f32_16x16x32_bf16(ah[i], bl[j], acc[i][j], 0,0,0);
        acc[i][j] = __builtin_amdgcn_mfma_f32_16x16x32_bf16(al[i], bh[j], acc[i][j], 0,0,0);
      }
  }

  const float bb = bS[0];
  float pj[4];
  #pragma unroll
  for (int j=0;j<4;++j) pj[j] = p[brow[j]];
  #pragma unroll
  for (int i=0;i<4;++i){
    #pragma unroll
    for (int r=0;r<4;++r){
      int row = bm + i*16 + kb*4 + r;
      if (row < N_TOT){
        float pi = p[row];
        #pragma unroll
        for (int j=0;j<4;++j){
          int col = bn + j*16 + lr;
          if (col < N_TOT)
            scores[(size_t)row*N_TOT + col] = fmaxf(pi + pj[j] + bb - 2.f*acc[i][j][r], 0.f);
        }
      }
    }
  }
}

// ---------------- exact per-row top-50 + softmax -------------------------------
__global__ __launch_bounds__(256) void topk_kernel(const float* __restrict__ scores,
                                                   int* __restrict__ idxO,
                                                   float* __restrict__ softO){
  const int row = blockIdx.x, tid = threadIdx.x;
  const float4* srow = (const float4*)(scores + (size_t)row*N_TOT);
  float4 v[10];
  #pragma unroll
  for (int s=0;s<10;++s){
    int fi = tid + s*256;
    v[s] = (fi < 2500) ? srow[fi] : make_float4(-1.f,-1.f,-1.f,-1.f);
  }
  float mx = -1.f;
  #pragma unroll
  for (int s=0;s<10;++s)
    mx = fmaxf(mx, fmaxf(fmaxf(v[s].x,v[s].y), fmaxf(v[s].z,v[s].w)));
  __shared__ float redf[4];
  __shared__ int cntS;
  float wm = waveMaxF(mx);
  if ((tid&63)==0) redf[tid>>6] = wm;
  __syncthreads();
  mx = fmaxf(fmaxf(redf[0],redf[1]), fmaxf(redf[2],redf[3]));

  unsigned lo = 0, hi = __float_as_uint(mx);
  while (lo < hi){
    unsigned mid = (lo + hi) >> 1;
    float t = __uint_as_float(mid);
    int c = 0;
    #pragma unroll
    for (int s=0;s<10;++s)
      c += (v[s].x>t) + (v[s].y>t) + (v[s].z>t) + (v[s].w>t);
    if (tid==0) cntS = 0;
    __syncthreads();
    c = waveSumI(c);
    if ((tid&63)==0) atomicAdd(&cntS, c);
    __syncthreads();
    int total = cntS;
    __syncthreads();
    if (total >= TK) lo = mid + 1; else hi = mid;
  }
  const float v50 = __uint_as_float(lo);

  __shared__ int   selIdx[TK];
  __shared__ float selVal[TK];
  __shared__ int cSel, cTie;
  if (tid==0){ cSel=0; cTie=0; }
  __syncthreads();
  #pragma unroll
  for (int s=0;s<10;++s){
    int base = 4*(tid + s*256);
    float vals[4] = {v[s].x, v[s].y, v[s].z, v[s].w};
    #pragma unroll
    for (int e=0;e<4;++e){
      if (vals[e] > v50){ int q = atomicAdd(&cSel,1); selIdx[q]=base+e; selVal[q]=vals[e]; }
    }
  }
  __syncthreads();
  const int m = cSel;
  #pragma unroll
  for (int s=0;s<10;++s){
    int base = 4*(tid + s*256);
    float vals[4] = {v[s].x, v[s].y, v[s].z, v[s].w};
    #pragma unroll
    for (int e=0;e<4;++e){
      if (vals[e] == v50){
        int q = atomicAdd(&cTie,1);
        if (m + q < TK){ selIdx[m+q]=base+e; selVal[m+q]=v50; }
      }
    }
  }
  __syncthreads();
  if (tid < 64){
    float e = (tid < TK) ? __expf(selVal[tid] - mx) : 0.f;
    float s = waveSumF(e);
    if (tid < TK){
      softO[row*TK + tid] = e / s;
      idxO [row*TK + tid] = selIdx[tid];
    }
  }
}

// ---------------- scatter soft into dense S ------------------------------------
__global__ void scatter_kernel(const int* __restrict__ idx, const float* __restrict__ soft,
                               float* __restrict__ S){
  int t = blockIdx.x*blockDim.x + threadIdx.x;
  if (t < N_TOT*TK){
    int i = t / TK;
    S[(size_t)i*N_TOT + idx[t]] = soft[t];
  }
}

// ---------------- loss = sum(dp*soft) + gamma*sum(soft) ------------------------
__global__ __launch_bounds__(256) void loss_kernel(const float* __restrict__ feat,
                                                   const float* __restrict__ xn,
                                                   const int* __restrict__ idx,
                                                   const float* __restrict__ soft,
                                                   float* __restrict__ lossOut){
  int row = blockIdx.x;
  int grp = threadIdx.x>>6, lane = threadIdx.x&63;
  const float2 a = ((const float2*)(feat + (size_t)row*CDIM))[lane];
  float acc = 0.f;
  for (int k=grp; k<TK; k+=4){
    int   j = idx [row*TK + k];
    float s = soft[row*TK + k];
    const float2 b = ((const float2*)(feat + (size_t)j*CDIM))[lane];
    float d = a.x*b.x + a.y*b.y;
    d = waveSumF(d);
    if (lane==0){
      float dp = fmaxf(xn[row] + xn[j] - 2.f*d, 0.f);
      acc += s*dp + GAMMA_REG*s;
    }
  }
  __shared__ float part[4];
  if (lane==0) part[grp] = acc;
  __syncthreads();
  if (threadIdx.x==0) atomicAdd(lossOut, part[0]+part[1]+part[2]+part[3]);
}

// ---------------- h[i][c] = relu(b1[c] + sum_k soft * X1[idx_k][c]) ------------
__global__ __launch_bounds__(256) void h_kernel(const float* __restrict__ X1,
                                                const int* __restrict__ idx,
                                                const float* __restrict__ soft,
                                                const float* __restrict__ b1,
                                                float* __restrict__ h){
  int row = blockIdx.x, c = threadIdx.x;
  __shared__ int   ji[TK];
  __shared__ float sv[TK];
  if (c < TK){ ji[c]=idx[row*TK+c]; sv[c]=soft[row*TK+c]; }
  __syncthreads();
  float acc = b1[c];
  #pragma unroll 10
  for (int k=0;k<TK;++k) acc = fmaf(sv[k], X1[(size_t)ji[k]*NHID_ + c], acc);
  h[(size_t)row*NHID_ + c] = fmaxf(acc, 0.f);
}

// ---------------- X2 = h @ W2 (W2 in LDS) --------------------------------------
__global__ __launch_bounds__(256) void x2_kernel(const float* __restrict__ h,
                                                 const float* __restrict__ W2,
                                                 float* __restrict__ X2){
  __shared__ float w[NHID_*NCLS];
  for (int i=threadIdx.x; i<NHID_*NCLS; i+=256) w[i] = W2[i];
  __syncthreads();
  int t = blockIdx.x*256 + threadIdx.x;
  if (t < N_TOT*NCLS){
    int r = t / NCLS, c = t % NCLS;
    float acc = 0.f;
    const float* hr = h + (size_t)r*NHID_;
    #pragma unroll 8
    for (int k=0;k<NHID_;++k) acc = fmaf(hr[k], w[k*NCLS+c], acc);
    X2[t] = acc;
  }
}

// ------- logits[i][c] = b2[c] + sum_k soft*X2[idx_k][c]; semi = log_softmax ----
__global__ __launch_bounds__(64) void logits_kernel(const float* __restrict__ X2,
                                                    const int* __restrict__ idx,
                                                    const float* __restrict__ soft,
                                                    const float* __restrict__ b2,
                                                    float* __restrict__ semi){
  int row = blockIdx.x, tid = threadIdx.x;
  __shared__ int   ji[TK];
  __shared__ float sv[TK];
  if (tid < TK){ ji[tid]=idx[row*TK+tid]; sv[tid]=soft[row*TK+tid]; }
  __syncthreads();
  float acc = 0.f;
  if (tid < NCLS){
    acc = b2[tid];
    for (int k=0;k<TK;++k) acc = fmaf(sv[k], X2[(size_t)ji[k]*NCLS + tid], acc);
  }
  float mv = (tid < NCLS) ? acc : -1e30f;
  #pragma unroll
  for (int o=8;o;o>>=1) mv = fmaxf(mv, __shfl_xor(mv,o,16));
  float e = (tid < NCLS) ? __expf(acc - mv) : 0.f;
  #pragma unroll
  for (int o=8;o;o>>=1) e += __shfl_xor(e,o,16);
  if (tid < NCLS) semi[row*NCLS + tid] = acc - mv - logf(e);
}

extern "C" void kernel_launch(void* const* d_in, const int* in_sizes, int n_in,
                              void* d_out, int out_size, void* d_ws, size_t ws_size,
                              hipStream_t stream){
  const float* inputs   = (const float*)d_in[0];
  const float* W_lin    = (const float*)d_in[1];
  const float* b_lin    = (const float*)d_in[2];
  const float* bn_gamma = (const float*)d_in[3];
  const float* bn_beta  = (const float*)d_in[4];
  const float* a_S      = (const float*)d_in[5];
  const float* b_S      = (const float*)d_in[6];
  const float* W1       = (const float*)d_in[7];
  const float* b1       = (const float*)d_in[8];
  const float* W2       = (const float*)d_in[9];
  const float* b2       = (const float*)d_in[10];

  float* out  = (float*)d_out;
  float* ws   = (float*)d_ws;

  // ws layout (float offsets), total 7,520,000 floats = 30.1 MB
  float*  feat = ws;                        // [0        .. 1,280,000)
  float*  p    = ws + 1280000;              // [1,280,000.. 1,290,000)
  float*  xn   = ws + 1290000;              // [1,290,000.. 1,300,000)
  int*    idxb = (int*)(ws + 1300000);      // [1,300,000.. 1,800,000)
  float*  soft = ws + 1800000;              // [1,800,000.. 2,300,000)
  float*  X1   = ws + 2300000;              // [2,300,000.. 4,860,000)
  // bf16 split buffers: each needs 1,280,000 ushorts = 640,000 floats.
  // They live in [4,860,000 .. 7,420,000) and are DEAD after score_mfma;
  // hbuf reuses the same region later (written at step 10).
  ushort* fh   = (ushort*)(ws + 4860000);
  ushort* fl   = (ushort*)(ws + 5500000);
  ushort* gh   = (ushort*)(ws + 6140000);
  ushort* gl   = (ushort*)(ws + 6780000);
  float*  hbuf = ws + 4860000;              // reuse of split region (after score)
  float*  X2   = ws + 7420000;              // [7,420,000.. 7,520,000)

  float* semi    = out;
  float* lossOut = out + 100000;
  float* Sout    = out + 100001;
  float* scratch = out + 100000;            // score scratch (overwritten later)

  // 1. lin = inputs @ W_lin + b_lin
  gemm64<true><<<dim3(2,157), 256, 0, stream>>>(inputs, W_lin, b_lin, feat, N_TOT, CDIM, 3072);
  // 2. per-chunk BN in place
  bn_kernel<<<100, CDIM, 0, stream>>>(feat, bn_gamma, bn_beta);
  // 3. bf16 splits + p, xn
  featsplit<<<2500, 256, 0, stream>>>(feat, a_S, fh, fl, gh, gl, p, xn);
  // 4. scores via split-bf16 MFMA -> scratch
  score_mfma<<<dim3(79,79), 256, 0, stream>>>(fh, fl, gh, gl, p, b_S, scratch);
  // 5. X1 = feat @ W1
  gemm64<false><<<dim3(4,157), 256, 0, stream>>>(feat, W1, nullptr, X1, N_TOT, NHID_, CDIM);
  // 6. exact top-50 + softmax
  topk_kernel<<<N_TOT, 256, 0, stream>>>(scratch, idxb, soft);
  // 7. zero loss + S (after topk has consumed scratch)
  hipMemsetAsync(lossOut, 0, (size_t)100000001*sizeof(float), stream);
  // 8. scatter S
  scatter_kernel<<<(N_TOT*TK+255)/256, 256, 0, stream>>>(idxb, soft, Sout);
  // 9. loss
  loss_kernel<<<N_TOT, 256, 0, stream>>>(feat, xn, idxb, soft, lossOut);
  // 10. h = relu(S@X1 + b1)  (hbuf overwrites dead split buffers)
  h_kernel<<<N_TOT, NHID_, 0, stream>>>(X1, idxb, soft, b1, hbuf);
  // 11. X2 = h @ W2
  x2_kernel<<<(N_TOT*NCLS+255)/256, 256, 0, stream>>>(hbuf, W2, X2);
  // 12. logits + log_softmax
  logits_kernel<<<N_TOT, 64, 0, stream>>>(X2, idxb, soft, b2, semi);
}

// Round 4
// 1435.016 us; speedup vs baseline: 1.1123x; 1.0288x over previous
//
#include <hip/hip_runtime.h>
#include <hip/hip_bf16.h>
#include <cstdint>
#include <cstddef>

#define N_TOT 10000
#define CDIM  128
#define TK    50
#define NHID_ 256
#define NCLS  10
#define GAMMA_REG 0.01f
#define BN_EPS 1e-5f

typedef float f32x4 __attribute__((ext_vector_type(4)));
typedef short s16x8 __attribute__((ext_vector_type(8)));

__device__ __forceinline__ float waveSumF(float v){
  #pragma unroll
  for (int o=32;o;o>>=1) v += __shfl_xor(v,o,64);
  return v;
}
__device__ __forceinline__ float waveMaxF(float v){
  #pragma unroll
  for (int o=32;o;o>>=1) v = fmaxf(v,__shfl_xor(v,o,64));
  return v;
}
__device__ __forceinline__ int waveSumI(int v){
  #pragma unroll
  for (int o=32;o;o>>=1) v += __shfl_xor(v,o,64);
  return v;
}
__device__ __forceinline__ ushort bfh(float f){
  __hip_bfloat16 h = __float2bfloat16(f);          // RNE
  return *reinterpret_cast<ushort*>(&h);
}
__device__ __forceinline__ float bf2f(ushort u){
  __hip_bfloat16 h = *reinterpret_cast<__hip_bfloat16*>(&u);
  return __bfloat162float(h);
}

// ---------------- generic 64x64 fp32 GEMM: C = A[MxK] @ B[KxN] (+bias) ----------
template<bool BIAS>
__global__ __launch_bounds__(256) void gemm64(const float* __restrict__ A,
                                              const float* __restrict__ B,
                                              const float* __restrict__ bias,
                                              float* __restrict__ C,
                                              int M, int N, int K){
  constexpr int BK=32;
  __shared__ float As[BK][64+4];
  __shared__ float Bs[BK][64+4];
  const int tid = threadIdx.x;
  const int bm = blockIdx.y*64, bn = blockIdx.x*64;
  const int tm = (tid>>4)<<2;
  const int tn = (tid&15)<<2;
  float acc[4][4] = {};
  for (int k0=0;k0<K;k0+=BK){
    #pragma unroll
    for (int i=0;i<2;++i){
      int fi = tid + i*256;
      int r  = fi>>3;
      int c4 = fi&7;
      float4 v = make_float4(0,0,0,0);
      int gr = bm + r;
      if (gr < M) v = *(const float4*)(A + (size_t)gr*K + k0 + (c4<<2));
      As[(c4<<2)+0][r]=v.x; As[(c4<<2)+1][r]=v.y; As[(c4<<2)+2][r]=v.z; As[(c4<<2)+3][r]=v.w;
    }
    #pragma unroll
    for (int i=0;i<2;++i){
      int fi = tid + i*256;
      int r  = fi>>4;
      int c4 = fi&15;
      float4 v = *(const float4*)(B + (size_t)(k0+r)*N + bn + (c4<<2));
      *(float4*)&Bs[r][c4<<2] = v;
    }
    __syncthreads();
    #pragma unroll
    for (int kk=0;kk<BK;++kk){
      float a[4], b[4];
      *(float4*)a = *(const float4*)&As[kk][tm];
      *(float4*)b = *(const float4*)&Bs[kk][tn];
      #pragma unroll
      for (int i=0;i<4;++i)
        #pragma unroll
        for (int j=0;j<4;++j) acc[i][j] = fmaf(a[i], b[j], acc[i][j]);
    }
    __syncthreads();
  }
  #pragma unroll
  for (int i=0;i<4;++i){
    int gr = bm+tm+i;
    if (gr < M){
      float4 o; o.x=acc[i][0]; o.y=acc[i][1]; o.z=acc[i][2]; o.w=acc[i][3];
      if (BIAS){
        o.x += bias[bn+tn+0]; o.y += bias[bn+tn+1];
        o.z += bias[bn+tn+2]; o.w += bias[bn+tn+3];
      }
      *(float4*)(C + (size_t)gr*N + bn + tn) = o;
    }
  }
}

// ---------------- per-chunk BatchNorm (training stats, biased var), in place ----
__global__ void bn_kernel(float* __restrict__ feat, const float* __restrict__ g,
                          const float* __restrict__ b){
  int chunk = blockIdx.x;
  int c = threadIdx.x;
  float* base = feat + (size_t)chunk*100*CDIM;
  float s=0.f, s2=0.f;
  for (int r=0;r<100;++r){ float v = base[r*CDIM+c]; s += v; s2 += v*v; }
  float mu  = s * 0.01f;
  float var = s2 * 0.01f - mu*mu;
  float sc  = g[c] * rsqrtf(var + BN_EPS);
  float sh  = b[c] - mu*sc;
  for (int r=0;r<100;++r){ base[r*CDIM+c] = base[r*CDIM+c]*sc + sh; }
}

// ------- split feat into bf16 hi/lo (plain: fh/fl, a-scaled: gh/gl) + p, xn ----
__global__ __launch_bounds__(256) void featsplit(const float* __restrict__ feat,
                                                 const float* __restrict__ aS,
                                                 ushort* __restrict__ fh, ushort* __restrict__ fl,
                                                 ushort* __restrict__ gh, ushort* __restrict__ gl,
                                                 float* __restrict__ p, float* __restrict__ xn){
  int wave = threadIdx.x>>6, lane = threadIdx.x&63;
  int row = blockIdx.x*4 + wave;
  const float2 f = ((const float2*)(feat + (size_t)row*CDIM))[lane];
  const float2 a = ((const float2*)aS)[lane];
  float gx = f.x*a.x, gy = f.y*a.y;

  ushort2 v;
  size_t o = (size_t)row*64 + lane;
  v.x = bfh(f.x); v.y = bfh(f.y);
  ((ushort2*)fh)[o] = v;
  ushort2 vl; vl.x = bfh(f.x - bf2f(v.x)); vl.y = bfh(f.y - bf2f(v.y));
  ((ushort2*)fl)[o] = vl;
  ushort2 w; w.x = bfh(gx); w.y = bfh(gy);
  ((ushort2*)gh)[o] = w;
  ushort2 wl2; wl2.x = bfh(gx - bf2f(w.x)); wl2.y = bfh(gy - bf2f(w.y));
  ((ushort2*)gl)[o] = wl2;

  float sp = gx*f.x + gy*f.y;
  float sx = f.x*f.x + f.y*f.y;
  sp = waveSumF(sp); sx = waveSumF(sx);
  if (lane==0){ p[row]=sp; xn[row]=sx; }
}

// -------- scores[i][j] = relu(p_i + p_j + b - 2 * (g_i . f_j)), split-bf16 MFMA -
// Register double-buffered prefetch over the 4 K-steps; XCD-chunked swizzle.
#define LOADK(AH, AL, BH, BL, K0)                                     \
  {                                                                    \
    _Pragma("unroll")                                                  \
    for (int i=0;i<4;++i){                                             \
      AH[i] = *(const s16x8*)(gh + aoff[i] + (K0));                    \
      AL[i] = *(const s16x8*)(gl + aoff[i] + (K0));                    \
      BH[i] = *(const s16x8*)(fh + boff[i] + (K0));                    \
      BL[i] = *(const s16x8*)(fl + boff[i] + (K0));                    \
    }                                                                  \
  }

#define MFMAS(AH, AL, BH, BL)                                          \
  {                                                                    \
    _Pragma("unroll")                                                  \
    for (int i=0;i<4;++i)                                              \
      _Pragma("unroll")                                                \
      for (int j=0;j<4;++j){                                           \
        acc[i][j] = __builtin_amdgcn_mfma_f32_16x16x32_bf16(AH[i], BH[j], acc[i][j], 0,0,0); \
        acc[i][j] = __builtin_amdgcn_mfma_f32_16x16x32_bf16(AH[i], BL[j], acc[i][j], 0,0,0); \
        acc[i][j] = __builtin_amdgcn_mfma_f32_16x16x32_bf16(AL[i], BH[j], acc[i][j], 0,0,0); \
      }                                                                \
  }

__global__ __launch_bounds__(256, 2) void score_mfma(const ushort* __restrict__ fh,
                                                     const ushort* __restrict__ fl,
                                                     const ushort* __restrict__ gh,
                                                     const ushort* __restrict__ gl,
                                                     const float* __restrict__ p,
                                                     const float* __restrict__ bS,
                                                     float* __restrict__ scores){
  const int lane = threadIdx.x & 63;
  const int wave = threadIdx.x >> 6;
  const int wm = wave >> 1, wn = wave & 1;

  // bijective XCD-chunk swizzle (m204): nwg=6241, 8 XCDs; col-major tile map
  const int nwg = 6241, q = nwg >> 3, r = nwg & 7;   // q=780, r=1
  int bid = blockIdx.x;
  int xcd = bid & 7, loc = bid >> 3;
  int wid = (xcd < r ? xcd*(q+1) : r*(q+1) + (xcd-r)*q) + loc;
  const int bxt = wid / 79;          // column tile (contiguous band per XCD)
  const int byt = wid % 79;          // row tile

  const int bm = byt*128 + wm*64;
  const int bn = bxt*128 + wn*64;
  const int lr = lane & 15;
  const int kb = lane >> 4;
  f32x4 acc[4][4] = {};

  int arow[4], brow[4];
  size_t aoff[4], boff[4];
  #pragma unroll
  for (int i=0;i<4;++i){
    int rr = bm + i*16 + lr; arow[i] = (rr < N_TOT ? rr : N_TOT-1);
    int cc = bn + i*16 + lr; brow[i] = (cc < N_TOT ? cc : N_TOT-1);
    aoff[i] = (size_t)arow[i]*CDIM + kb*8;
    boff[i] = (size_t)brow[i]*CDIM + kb*8;
  }

  s16x8 pah[4],pal[4],pbh[4],pbl[4];
  s16x8 qah[4],qal[4],qbh[4],qbl[4];
  LOADK(pah,pal,pbh,pbl, 0);
  LOADK(qah,qal,qbh,qbl, 32);
  MFMAS(pah,pal,pbh,pbl);
  LOADK(pah,pal,pbh,pbl, 64);
  MFMAS(qah,qal,qbh,qbl);
  LOADK(qah,qal,qbh,qbl, 96);
  MFMAS(pah,pal,pbh,pbl);
  MFMAS(qah,qal,qbh,qbl);

  const float bb = bS[0];
  float pj[4];
  #pragma unroll
  for (int j=0;j<4;++j) pj[j] = p[brow[j]];
  #pragma unroll
  for (int i=0;i<4;++i){
    #pragma unroll
    for (int rr=0;rr<4;++rr){
      int row = bm + i*16 + kb*4 + rr;
      if (row < N_TOT){
        float pi = p[row];
        #pragma unroll
        for (int j=0;j<4;++j){
          int col = bn + j*16 + lr;
          if (col < N_TOT)
            scores[(size_t)row*N_TOT + col] = fmaxf(pi + pj[j] + bb - 2.f*acc[i][j][rr], 0.f);
        }
      }
    }
  }
}

// ---------------- exact per-row top-50 + softmax -------------------------------
__global__ __launch_bounds__(256) void topk_kernel(const float* __restrict__ scores,
                                                   int* __restrict__ idxO,
                                                   float* __restrict__ softO){
  const int row = blockIdx.x, tid = threadIdx.x;
  const float4* srow = (const float4*)(scores + (size_t)row*N_TOT);
  float4 v[10];
  #pragma unroll
  for (int s=0;s<10;++s){
    int fi = tid + s*256;
    v[s] = (fi < 2500) ? srow[fi] : make_float4(-1.f,-1.f,-1.f,-1.f);
  }
  float mx = -1.f;
  #pragma unroll
  for (int s=0;s<10;++s)
    mx = fmaxf(mx, fmaxf(fmaxf(v[s].x,v[s].y), fmaxf(v[s].z,v[s].w)));
  __shared__ float redf[4];
  __shared__ int cntS;
  float wm = waveMaxF(mx);
  if ((tid&63)==0) redf[tid>>6] = wm;
  __syncthreads();
  mx = fmaxf(fmaxf(redf[0],redf[1]), fmaxf(redf[2],redf[3]));

  unsigned lo = 0, hi = __float_as_uint(mx);
  while (lo < hi){
    unsigned mid = (lo + hi) >> 1;
    float t = __uint_as_float(mid);
    int c = 0;
    #pragma unroll
    for (int s=0;s<10;++s)
      c += (v[s].x>t) + (v[s].y>t) + (v[s].z>t) + (v[s].w>t);
    if (tid==0) cntS = 0;
    __syncthreads();
    c = waveSumI(c);
    if ((tid&63)==0) atomicAdd(&cntS, c);
    __syncthreads();
    int total = cntS;
    __syncthreads();
    if (total >= TK) lo = mid + 1; else hi = mid;
  }
  const float v50 = __uint_as_float(lo);

  __shared__ int   selIdx[TK];
  __shared__ float selVal[TK];
  __shared__ int cSel, cTie;
  if (tid==0){ cSel=0; cTie=0; }
  __syncthreads();
  #pragma unroll
  for (int s=0;s<10;++s){
    int base = 4*(tid + s*256);
    float vals[4] = {v[s].x, v[s].y, v[s].z, v[s].w};
    #pragma unroll
    for (int e=0;e<4;++e){
      if (vals[e] > v50){ int q = atomicAdd(&cSel,1); selIdx[q]=base+e; selVal[q]=vals[e]; }
    }
  }
  __syncthreads();
  const int m = cSel;
  #pragma unroll
  for (int s=0;s<10;++s){
    int base = 4*(tid + s*256);
    float vals[4] = {v[s].x, v[s].y, v[s].z, v[s].w};
    #pragma unroll
    for (int e=0;e<4;++e){
      if (vals[e] == v50){
        int q = atomicAdd(&cTie,1);
        if (m + q < TK){ selIdx[m+q]=base+e; selVal[m+q]=v50; }
      }
    }
  }
  __syncthreads();
  if (tid < 64){
    float e = (tid < TK) ? __expf(selVal[tid] - mx) : 0.f;
    float s = waveSumF(e);
    if (tid < TK){
      softO[row*TK + tid] = e / s;
      idxO [row*TK + tid] = selIdx[tid];
    }
  }
}

// ---------------- scatter soft into dense S ------------------------------------
__global__ void scatter_kernel(const int* __restrict__ idx, const float* __restrict__ soft,
                               float* __restrict__ S){
  int t = blockIdx.x*blockDim.x + threadIdx.x;
  if (t < N_TOT*TK){
    int i = t / TK;
    S[(size_t)i*N_TOT + idx[t]] = soft[t];
  }
}

// ---------------- loss = sum(dp*soft) + gamma*sum(soft) ------------------------
__global__ __launch_bounds__(256) void loss_kernel(const float* __restrict__ feat,
                                                   const float* __restrict__ xn,
                                                   const int* __restrict__ idx,
                                                   const float* __restrict__ soft,
                                                   float* __restrict__ lossOut){
  int row = blockIdx.x;
  int grp = threadIdx.x>>6, lane = threadIdx.x&63;
  const float2 a = ((const float2*)(feat + (size_t)row*CDIM))[lane];
  float acc = 0.f;
  for (int k=grp; k<TK; k+=4){
    int   j = idx [row*TK + k];
    float s = soft[row*TK + k];
    const float2 b = ((const float2*)(feat + (size_t)j*CDIM))[lane];
    float d = a.x*b.x + a.y*b.y;
    d = waveSumF(d);
    if (lane==0){
      float dp = fmaxf(xn[row] + xn[j] - 2.f*d, 0.f);
      acc += s*dp + GAMMA_REG*s;
    }
  }
  __shared__ float part[4];
  if (lane==0) part[grp] = acc;
  __syncthreads();
  if (threadIdx.x==0) atomicAdd(lossOut, part[0]+part[1]+part[2]+part[3]);
}

// ---------------- h[i][c] = relu(b1[c] + sum_k soft * X1[idx_k][c]) ------------
__global__ __launch_bounds__(256) void h_kernel(const float* __restrict__ X1,
                                                const int* __restrict__ idx,
                                                const float* __restrict__ soft,
                                                const float* __restrict__ b1,
                                                float* __restrict__ h){
  int row = blockIdx.x, c = threadIdx.x;
  __shared__ int   ji[TK];
  __shared__ float sv[TK];
  if (c < TK){ ji[c]=idx[row*TK+c]; sv[c]=soft[row*TK+c]; }
  __syncthreads();
  float acc = b1[c];
  #pragma unroll 10
  for (int k=0;k<TK;++k) acc = fmaf(sv[k], X1[(size_t)ji[k]*NHID_ + c], acc);
  h[(size_t)row*NHID_ + c] = fmaxf(acc, 0.f);
}

// ---------------- X2 = h @ W2 (W2 in LDS) --------------------------------------
__global__ __launch_bounds__(256) void x2_kernel(const float* __restrict__ h,
                                                 const float* __restrict__ W2,
                                                 float* __restrict__ X2){
  __shared__ float w[NHID_*NCLS];
  for (int i=threadIdx.x; i<NHID_*NCLS; i+=256) w[i] = W2[i];
  __syncthreads();
  int t = blockIdx.x*256 + threadIdx.x;
  if (t < N_TOT*NCLS){
    int r = t / NCLS, c = t % NCLS;
    float acc = 0.f;
    const float* hr = h + (size_t)r*NHID_;
    #pragma unroll 8
    for (int k=0;k<NHID_;++k) acc = fmaf(hr[k], w[k*NCLS+c], acc);
    X2[t] = acc;
  }
}

// ------- logits[i][c] = b2[c] + sum_k soft*X2[idx_k][c]; semi = log_softmax ----
__global__ __launch_bounds__(64) void logits_kernel(const float* __restrict__ X2,
                                                    const int* __restrict__ idx,
                                                    const float* __restrict__ soft,
                                                    const float* __restrict__ b2,
                                                    float* __restrict__ semi){
  int row = blockIdx.x, tid = threadIdx.x;
  __shared__ int   ji[TK];
  __shared__ float sv[TK];
  if (tid < TK){ ji[tid]=idx[row*TK+tid]; sv[tid]=soft[row*TK+tid]; }
  __syncthreads();
  float acc = 0.f;
  if (tid < NCLS){
    acc = b2[tid];
    for (int k=0;k<TK;++k) acc = fmaf(sv[k], X2[(size_t)ji[k]*NCLS + tid], acc);
  }
  float mv = (tid < NCLS) ? acc : -1e30f;
  #pragma unroll
  for (int o=8;o;o>>=1) mv = fmaxf(mv, __shfl_xor(mv,o,16));
  float e = (tid < NCLS) ? __expf(acc - mv) : 0.f;
  #pragma unroll
  for (int o=8;o;o>>=1) e += __shfl_xor(e,o,16);
  if (tid < NCLS) semi[row*NCLS + tid] = acc - mv - logf(e);
}

extern "C" void kernel_launch(void* const* d_in, const int* in_sizes, int n_in,
                              void* d_out, int out_size, void* d_ws, size_t ws_size,
                              hipStream_t stream){
  const float* inputs   = (const float*)d_in[0];
  const float* W_lin    = (const float*)d_in[1];
  const float* b_lin    = (const float*)d_in[2];
  const float* bn_gamma = (const float*)d_in[3];
  const float* bn_beta  = (const float*)d_in[4];
  const float* a_S      = (const float*)d_in[5];
  const float* b_S      = (const float*)d_in[6];
  const float* W1       = (const float*)d_in[7];
  const float* b1       = (const float*)d_in[8];
  const float* W2       = (const float*)d_in[9];
  const float* b2       = (const float*)d_in[10];

  float* out  = (float*)d_out;
  float* ws   = (float*)d_ws;

  // ws layout (float offsets), total 7,520,000 floats = 30.1 MB
  float*  feat = ws;                        // [0        .. 1,280,000)
  float*  p    = ws + 1280000;              // [1,280,000.. 1,290,000)
  float*  xn   = ws + 1290000;              // [1,290,000.. 1,300,000)
  int*    idxb = (int*)(ws + 1300000);      // [1,300,000.. 1,800,000)
  float*  soft = ws + 1800000;              // [1,800,000.. 2,300,000)
  float*  X1   = ws + 2300000;              // [2,300,000.. 4,860,000)
  // bf16 split buffers: each 1,280,000 ushorts = 640,000 floats.
  // Dead after score_mfma; hbuf reuses the region at step 10.
  ushort* fh   = (ushort*)(ws + 4860000);
  ushort* fl   = (ushort*)(ws + 5500000);
  ushort* gh   = (ushort*)(ws + 6140000);
  ushort* gl   = (ushort*)(ws + 6780000);
  float*  hbuf = ws + 4860000;              // reuse of split region (after score)
  float*  X2   = ws + 7420000;              // [7,420,000.. 7,520,000)

  float* semi    = out;
  float* lossOut = out + 100000;
  float* Sout    = out + 100001;
  float* scratch = out + 100000;            // score scratch (overwritten later)

  // 1. lin = inputs @ W_lin + b_lin
  gemm64<true><<<dim3(2,157), 256, 0, stream>>>(inputs, W_lin, b_lin, feat, N_TOT, CDIM, 3072);
  // 2. per-chunk BN in place
  bn_kernel<<<100, CDIM, 0, stream>>>(feat, bn_gamma, bn_beta);
  // 3. bf16 splits + p, xn
  featsplit<<<2500, 256, 0, stream>>>(feat, a_S, fh, fl, gh, gl, p, xn);
  // 4. scores via split-bf16 MFMA (prefetched, XCD-swizzled) -> scratch
  score_mfma<<<6241, 256, 0, stream>>>(fh, fl, gh, gl, p, b_S, scratch);
  // 5. X1 = feat @ W1
  gemm64<false><<<dim3(4,157), 256, 0, stream>>>(feat, W1, nullptr, X1, N_TOT, NHID_, CDIM);
  // 6. exact top-50 + softmax
  topk_kernel<<<N_TOT, 256, 0, stream>>>(scratch, idxb, soft);
  // 7. zero loss + S (after topk has consumed scratch)
  hipMemsetAsync(lossOut, 0, (size_t)100000001*sizeof(float), stream);
  // 8. scatter S
  scatter_kernel<<<(N_TOT*TK+255)/256, 256, 0, stream>>>(idxb, soft, Sout);
  // 9. loss
  loss_kernel<<<N_TOT, 256, 0, stream>>>(feat, xn, idxb, soft, lossOut);
  // 10. h = relu(S@X1 + b1)  (hbuf overwrites dead split buffers)
  h_kernel<<<N_TOT, NHID_, 0, stream>>>(X1, idxb, soft, b1, hbuf);
  // 11. X2 = h @ W2
  x2_kernel<<<(N_TOT*NCLS+255)/256, 256, 0, stream>>>(hbuf, W2, X2);
  // 12. logits + log_softmax
  logits_kernel<<<N_TOT, 64, 0, stream>>>(X2, idxb, soft, b2, semi);
}